// Round 1
// baseline (66.904 us; speedup 1.0000x reference)
//
#include <hip/hip_runtime.h>
#include <math.h>

#define NDIM 1024
#define BDIM 128
#define TS 32
#define NT (NDIM / TS)                 // 32
#define NTILES (NT * (NT + 1) / 2)     // 528 upper-tri tiles

// One block per upper-tri 32x32 tile. Per tile row i (masked to triu):
//   contribution(b) = q_bi * RS_i + r_bi * (sum_j W_ij * v_bj)
// with q=1-v, r=2v-1, RS_i = masked row sum. 1 MAC per W element.
// Lane l owns b0=l, b1=l+64; wave w owns tile rows [8w, 8w+8).
//
// W is read through WAVE-UNIFORM addresses in the FMA loop -> scalar/SGPR
// path (or L1 broadcast), zero LDS traffic for W.
// V slices staged in natural [b][j] float4 layout with XOR bank swizzle:
// 8 b128 writes + 20 b128 reads per wave instead of the old transpose
// (128 b32 writes + 320 b32 reads per block).
__global__ __launch_bounds__(256) void potts_main(
    const float* __restrict__ V,      // [128][1024]
    const float* __restrict__ W,      // [1024][1024]
    float* __restrict__ partial)      // [NTILES][128]
{
    const int t = blockIdx.x;
    // closed-form upper-tri tile index (exact at triangular boundaries; fixup guards rounding)
    const int u = NTILES - 1 - t;
    int kk = (int)(0.5f * (sqrtf((float)(8 * u + 1)) - 1.0f));
    if (kk * (kk + 1) / 2 > u) --kk;
    if ((kk + 1) * (kk + 2) / 2 <= u) ++kk;
    const int ti = NT - 1 - kk;
    const int tj = NT - 1 - (u - kk * (kk + 1) / 2);
    const int I0 = ti * TS, J0 = tj * TS;
    const bool diag = (ti == tj);

    __shared__ float4 vj4[BDIM][8];     // V[b][J0+4*j4..+4] at column j4^(b&7)
    __shared__ float4 vi4[BDIM][8];     // V[b][I0+4*j4..+4] at column j4^(b&7)
    __shared__ float rs[TS];            // masked row sums
    __shared__ float red[4][BDIM];

    const int tid = threadIdx.x;
    const int w = tid >> 6;
    const int l = tid & 63;
    const int l7 = l & 7;

    // ---- masked W row sums via one float4/thread + 8-lane shfl reduce
    {
        const int r = tid >> 3, c4 = (tid & 7) * 4;
        float4 w4 = *(const float4*)(W + (size_t)(I0 + r) * NDIM + (J0 + c4));
        if (diag) {                      // triu: keep j >= i
            if (c4 + 0 < r) w4.x = 0.0f;
            if (c4 + 1 < r) w4.y = 0.0f;
            if (c4 + 2 < r) w4.z = 0.0f;
            if (c4 + 3 < r) w4.w = 0.0f;
        }
        float rsum = (w4.x + w4.y) + (w4.z + w4.w);
        rsum += __shfl_xor(rsum, 1);
        rsum += __shfl_xor(rsum, 2);
        rsum += __shfl_xor(rsum, 4);
        if ((tid & 7) == 0) rs[r] = rsum;
    }

    // ---- stage V slices, natural orientation, swizzled float4 columns
#pragma unroll
    for (int it = 0; it < 4; ++it) {
        const int fid = tid + 256 * it;       // 0..1023
        const int b = fid >> 3, j4 = fid & 7;
        const int g = j4 ^ (b & 7);
        vj4[b][g] = *(const float4*)(V + (size_t)b * NDIM + (J0 + 4 * j4));
        vi4[b][g] = *(const float4*)(V + (size_t)b * NDIM + (I0 + 4 * j4));
    }
    __syncthreads();

    // ---- per-lane vj registers (b128 reads, swizzle-matched)
    float vj0[TS], vj1[TS];
#pragma unroll
    for (int j4 = 0; j4 < 8; ++j4) {
        const int g = j4 ^ l7;
        const float4 a = vj4[l][g];
        vj0[4*j4+0] = a.x; vj0[4*j4+1] = a.y;
        vj0[4*j4+2] = a.z; vj0[4*j4+3] = a.w;
        const float4 c = vj4[l + 64][g];
        vj1[4*j4+0] = c.x; vj1[4*j4+1] = c.y;
        vj1[4*j4+2] = c.z; vj1[4*j4+3] = c.w;
    }
    // ---- per-lane vi registers: this wave's 8 tile rows
    float vi0[8], vi1[8];
    {
        const int ga = (2 * w) ^ l7, gb = (2 * w + 1) ^ l7;
        const float4 p  = vi4[l][ga],      q  = vi4[l][gb];
        const float4 p1 = vi4[l + 64][ga], q1 = vi4[l + 64][gb];
        vi0[0]=p.x;  vi0[1]=p.y;  vi0[2]=p.z;  vi0[3]=p.w;
        vi0[4]=q.x;  vi0[5]=q.y;  vi0[6]=q.z;  vi0[7]=q.w;
        vi1[0]=p1.x; vi1[1]=p1.y; vi1[2]=p1.z; vi1[3]=p1.w;
        vi1[4]=q1.x; vi1[5]=q1.y; vi1[6]=q1.z; vi1[7]=q1.w;
    }

    float acc0 = 0.0f, acc1 = 0.0f;
#pragma unroll
    for (int k = 0; k < 8; ++k) {
        const int i = 8 * w + k;
        // wave-uniform row pointer -> scalar loads (SGPR operand in the FMAs)
        const float* __restrict__ wrow = W + (size_t)(I0 + i) * NDIM + J0;
        float za0 = 0.f, zb0 = 0.f, za1 = 0.f, zb1 = 0.f;
#pragma unroll
        for (int j = 0; j < TS; j += 2) {
            float wa = wrow[j];
            float wb = wrow[j + 1];
            if (diag) {                  // uniform select, stays on scalar path
                if (j < i)     wa = 0.0f;
                if (j + 1 < i) wb = 0.0f;
            }
            za0 = fmaf(wa, vj0[j],     za0);
            zb0 = fmaf(wb, vj0[j + 1], zb0);
            za1 = fmaf(wa, vj1[j],     za1);
            zb1 = fmaf(wb, vj1[j + 1], zb1);
        }
        const float y0 = vi0[k], y1 = vi1[k];
        const float rsk = rs[i];
        acc0 = fmaf(1.0f - y0, rsk, acc0);
        acc0 = fmaf(2.0f * y0 - 1.0f, za0 + zb0, acc0);
        acc1 = fmaf(1.0f - y1, rsk, acc1);
        acc1 = fmaf(2.0f * y1 - 1.0f, za1 + zb1, acc1);
    }

    red[w][l] = acc0;
    red[w][l + 64] = acc1;
    __syncthreads();
    if (tid < BDIM) {
        partial[t * BDIM + tid] =
            (red[0][tid] + red[1][tid]) + (red[2][tid] + red[3][tid]);
    }
}

// ---- reduce 528 tile partials -> out[b]; one block per b, latency-pipelined
__global__ __launch_bounds__(64) void potts_red(
    const float* __restrict__ partial, float* __restrict__ out)
{
    const int b = blockIdx.x;
    const int lane = threadIdx.x;
    float a0 = 0.f, a1 = 0.f;
    int t = lane;
#pragma unroll 4
    for (; t + 64 < NTILES; t += 128) {       // 2 indep chains, 9 loads/lane total
        a0 += partial[t * BDIM + b];
        a1 += partial[(t + 64) * BDIM + b];
    }
    if (t < NTILES) a0 += partial[t * BDIM + b];
    float a = a0 + a1;
#pragma unroll
    for (int off = 32; off > 0; off >>= 1)
        a += __shfl_down(a, off);
    if (lane == 0) out[b] = a;
}

extern "C" void kernel_launch(void* const* d_in, const int* in_sizes, int n_in,
                              void* d_out, int out_size, void* d_ws, size_t ws_size,
                              hipStream_t stream) {
    const float* V = (const float*)d_in[0];
    const float* W = (const float*)d_in[1];
    float* out = (float*)d_out;
    float* partial = (float*)d_ws;            // 528*128*4 = 270336 B

    potts_main<<<dim3(NTILES), dim3(256), 0, stream>>>(V, W, partial);
    potts_red<<<dim3(BDIM), dim3(64), 0, stream>>>(partial, out);
}